// Round 14
// baseline (572.885 us; speedup 1.0000x reference)
//
#include <hip/hip_runtime.h>
#include <hip/hip_bf16.h>
#include <hip/hip_cooperative_groups.h>
#include <math.h>

#define FH 128   // feature width of x and all hidden layers

typedef __attribute__((ext_vector_type(8))) short short8v;   // 8 bf16 (4 VGPRs)
typedef __attribute__((ext_vector_type(4))) float float4v;
typedef unsigned short ushort_t;
typedef unsigned int   uint32;

__device__ __forceinline__ ushort_t f2bf(float f) {          // RNE float->bf16
    uint32 u = __builtin_bit_cast(uint32, f);
    u += 0x7fffu + ((u >> 16) & 1u);
    return (ushort_t)(u >> 16);
}
__device__ __forceinline__ float bf_lo(uint32 w) { return __builtin_bit_cast(float, w << 16); }
__device__ __forceinline__ float bf_hi(uint32 w) { return __builtin_bit_cast(float, w & 0xffff0000u); }
__device__ __forceinline__ uint32 pack2(float lo, float hi) {
    return (uint32)f2bf(lo) | ((uint32)f2bf(hi) << 16);
}

// ---------------------------------------------------------------------------
// pack: Bp[((nt*8+kt)*64 + lane)*8 + j] = W[k][n],
//   nt=n>>4, kt=k>>5, lane=(n&15)+16*((k>>3)&3), j=k&7   (W = [Wl;Wr], 256x128)
__device__ __forceinline__ void pack_one(const float* __restrict__ Wl,
                                         const float* __restrict__ Wr,
                                         ushort_t* __restrict__ Bp, int t) {
    int k = t >> 7, n = t & 127;
    float v = (k < FH) ? Wl[k * FH + n] : Wr[(k - FH) * FH + n];
    int nt = n >> 4, kt = k >> 5;
    int lane = (n & 15) + (((k >> 3) & 3) << 4);
    int j = k & 7;
    Bp[(((nt * 8 + kt) * 64) + lane) * 8 + j] = f2bf(v);
}

// prep: cvt x->bf16 | 3 weight packs
__global__ __launch_bounds__(256) void prep_kernel(
        const float* __restrict__ x, ushort_t* __restrict__ xb, size_t n, int cvtBlocks,
        const float* __restrict__ Wl1, const float* __restrict__ Wr1, ushort_t* __restrict__ Bp1,
        const float* __restrict__ Wl2, const float* __restrict__ Wr2, ushort_t* __restrict__ Bp2,
        const float* __restrict__ Wl3, const float* __restrict__ Wr3, ushort_t* __restrict__ Bp3) {
    int b = blockIdx.x;
    if (b < cvtBlocks) {
        size_t base = ((size_t)b * 256 + threadIdx.x) * 8;
        if (base >= n) return;
        const float4 a = *(const float4*)(x + base);
        const float4 c = *(const float4*)(x + base + 4);
        ushort_t o[8] = {f2bf(a.x), f2bf(a.y), f2bf(a.z), f2bf(a.w),
                         f2bf(c.x), f2bf(c.y), f2bf(c.z), f2bf(c.w)};
        *(uint4*)(xb + base) = *(const uint4*)o;
        return;
    }
    b -= cvtBlocks;
    {                                            // weight packs (384 blocks)
        int which = b >> 7;
        int t = (b & 127) * 256 + threadIdx.x;
        if (which == 0)      pack_one(Wl1, Wr1, Bp1, t);
        else if (which == 1) pack_one(Wl2, Wr2, Bp2, t);
        else                 pack_one(Wl3, Wr3, Bp3, t);
    }
}

// ---------------------------------------------------------------------------
// Cooperative CSR build: zero-deg | deg count | scan1+gbounds | scan3 | fill,
// separated by grid syncs. 1024 blocks x 256 thr (4 blocks/CU, co-resident).
__global__ __launch_bounds__(256) void csr_coop_kernel(const int* __restrict__ src,
                                                       const int* __restrict__ dst,
                                                       int* __restrict__ deg,
                                                       int* __restrict__ rowptr,
                                                       int* __restrict__ pos,
                                                       int* __restrict__ csr,
                                                       int* __restrict__ blockSums,
                                                       const int* __restrict__ batch,
                                                       int* __restrict__ gstart,
                                                       int N, int E, int G, int nb) {
    cooperative_groups::grid_group grid = cooperative_groups::this_grid();
    const int t   = threadIdx.x;
    const int bid = blockIdx.x;
    const int nthr = gridDim.x * 256;
    const int gtid = bid * 256 + t;

    // ---- phase 0: zero deg
    for (int i = gtid; i < N; i += nthr) deg[i] = 0;
    grid.sync();

    // ---- phase A: in-degree count
    for (int e = gtid; e < E; e += nthr) atomicAdd(&deg[dst[e]], 1);
    grid.sync();

    // ---- phase B: per-block exclusive scan (blocks 0..nb-1), gbounds after
    if (bid < nb) {
        __shared__ int lds[256];
        const int base = bid * 1024;
        int v[4]; int sum = 0;
        #pragma unroll
        for (int j = 0; j < 4; ++j) {
            int idx = base + t * 4 + j;
            v[j] = (idx < N) ? deg[idx] : 0;
            sum += v[j];
        }
        lds[t] = sum; __syncthreads();
        for (int off = 1; off < 256; off <<= 1) {
            int val = lds[t];
            int add = (t >= off) ? lds[t - off] : 0;
            __syncthreads();
            lds[t] = val + add;
            __syncthreads();
        }
        int run = (t > 0) ? lds[t - 1] : 0;
        #pragma unroll
        for (int j = 0; j < 4; ++j) {
            int idx = base + t * 4 + j;
            if (idx < N) rowptr[idx] = run;
            run += v[j];
        }
        if (t == 255) blockSums[bid] = lds[255];
    } else if (bid < nb + 2) {                   // group bounds (sorted batch)
        int g = (bid - nb) * 256 + t;
        if (g <= G) {
            int lo = 0, hi = N;
            while (lo < hi) {
                int mid = (lo + hi) >> 1;
                if (batch[mid] < g) lo = mid + 1; else hi = mid;
            }
            gstart[g] = lo;
        }
    }
    grid.sync();

    // ---- phase C: add cross-block offsets, write pos[], rowptr[N]
    if (bid < nb) {
        __shared__ int sAdd, sTot;
        if (t < 64) {
            int pre = 0, tot = 0;
            for (int i = t; i < nb; i += 64) {
                const int v = blockSums[i];
                tot += v;
                if (i < bid) pre += v;
            }
            #pragma unroll
            for (int off = 1; off < 64; off <<= 1) {
                pre += __shfl_xor(pre, off);
                tot += __shfl_xor(tot, off);
            }
            if (t == 0) { sAdd = pre; sTot = tot; }
        }
        __syncthreads();
        const int add = sAdd;
        const int base = bid * 1024;
        #pragma unroll
        for (int j = 0; j < 4; ++j) {
            int idx = base + t * 4 + j;
            if (idx < N) {
                int v = rowptr[idx] + add;
                rowptr[idx] = v;
                pos[idx] = v;
            }
        }
        if (bid == nb - 1 && t == 0) rowptr[N] = sTot;
    }
    grid.sync();

    // ---- phase D: fill csr (2 edges/thread, int2 loads)
    for (int e = gtid * 2; e < E; e += nthr * 2) {
        if (e + 1 < E) {
            const int2 s2 = *(const int2*)(src + e);
            const int2 d2 = *(const int2*)(dst + e);
            int i0 = atomicAdd(&pos[d2.x], 1);
            int i1 = atomicAdd(&pos[d2.y], 1);
            csr[i0] = s2.x;
            csr[i1] = s2.y;
        } else {
            int idx = atomicAdd(&pos[dst[e]], 1);
            csr[idx] = src[e];
        }
    }
}

// ---------------------------------------------------------------------------
// pull aggregation (bf16 in/out, fp32 accumulate): one wave per dst node.
// 6-deep predicated prologue: covers deg<=24 (Poisson(12): ~99.9% of nodes)
// with all row loads independent & in flight; rare tail loop beyond.
__global__ __launch_bounds__(256) void pull_mean_kernel(const ushort_t* __restrict__ x,
                                                        const int* __restrict__ rowptr,
                                                        const int* __restrict__ csr,
                                                        ushort_t* __restrict__ aggr, int N) {
    const int v = (blockIdx.x * 256 + threadIdx.x) >> 6;
    if (v >= N) return;
    const int lane = threadIdx.x & 63;
    const int grp  = lane >> 4;        // which of 4 concurrent edges
    const int li   = lane & 15;        // uint4 column within the row
    const int beg = rowptr[v], end = rowptr[v + 1];
    const uint4* xp = (const uint4*)x + li;    // row = 16 uint4 (256B)

    const uint4 z = {0u, 0u, 0u, 0u};
    uint4 w0 = z, w1 = z, w2 = z, w3 = z, w4 = z, w5 = z;
    const int i0 = beg + grp;
    if (i0 < end)      w0 = xp[(size_t)csr[i0] * 16];
    if (i0 + 4 < end)  w1 = xp[(size_t)csr[i0 + 4] * 16];
    if (i0 + 8 < end)  w2 = xp[(size_t)csr[i0 + 8] * 16];
    if (i0 + 12 < end) w3 = xp[(size_t)csr[i0 + 12] * 16];
    if (i0 + 16 < end) w4 = xp[(size_t)csr[i0 + 16] * 16];
    if (i0 + 20 < end) w5 = xp[(size_t)csr[i0 + 20] * 16];

    float a0 = (bf_lo(w0.x) + bf_lo(w1.x)) + (bf_lo(w2.x) + bf_lo(w3.x)) + (bf_lo(w4.x) + bf_lo(w5.x));
    float a1 = (bf_hi(w0.x) + bf_hi(w1.x)) + (bf_hi(w2.x) + bf_hi(w3.x)) + (bf_hi(w4.x) + bf_hi(w5.x));
    float a2 = (bf_lo(w0.y) + bf_lo(w1.y)) + (bf_lo(w2.y) + bf_lo(w3.y)) + (bf_lo(w4.y) + bf_lo(w5.y));
    float a3 = (bf_hi(w0.y) + bf_hi(w1.y)) + (bf_hi(w2.y) + bf_hi(w3.y)) + (bf_hi(w4.y) + bf_hi(w5.y));
    float a4 = (bf_lo(w0.z) + bf_lo(w1.z)) + (bf_lo(w2.z) + bf_lo(w3.z)) + (bf_lo(w4.z) + bf_lo(w5.z));
    float a5 = (bf_hi(w0.z) + bf_hi(w1.z)) + (bf_hi(w2.z) + bf_hi(w3.z)) + (bf_hi(w4.z) + bf_hi(w5.z));
    float a6 = (bf_lo(w0.w) + bf_lo(w1.w)) + (bf_lo(w2.w) + bf_lo(w3.w)) + (bf_lo(w4.w) + bf_lo(w5.w));
    float a7 = (bf_hi(w0.w) + bf_hi(w1.w)) + (bf_hi(w2.w) + bf_hi(w3.w)) + (bf_hi(w4.w) + bf_hi(w5.w));

    for (int i = beg + 24 + grp; i < end; i += 4) {   // rare tail (deg > 24)
        const uint4 w = xp[(size_t)csr[i] * 16];
        a0 += bf_lo(w.x); a1 += bf_hi(w.x); a2 += bf_lo(w.y); a3 += bf_hi(w.y);
        a4 += bf_lo(w.z); a5 += bf_hi(w.z); a6 += bf_lo(w.w); a7 += bf_hi(w.w);
    }

    // combine the 4 group partials
    a0 += __shfl_xor(a0, 16); a1 += __shfl_xor(a1, 16);
    a2 += __shfl_xor(a2, 16); a3 += __shfl_xor(a3, 16);
    a4 += __shfl_xor(a4, 16); a5 += __shfl_xor(a5, 16);
    a6 += __shfl_xor(a6, 16); a7 += __shfl_xor(a7, 16);
    a0 += __shfl_xor(a0, 32); a1 += __shfl_xor(a1, 32);
    a2 += __shfl_xor(a2, 32); a3 += __shfl_xor(a3, 32);
    a4 += __shfl_xor(a4, 32); a5 += __shfl_xor(a5, 32);
    a6 += __shfl_xor(a6, 32); a7 += __shfl_xor(a7, 32);

    if (grp == 0) {
        const float inv = 1.0f / (float)max(end - beg, 1);
        uint4 o;
        o.x = pack2(a0 * inv, a1 * inv);
        o.y = pack2(a2 * inv, a3 * inv);
        o.z = pack2(a4 * inv, a5 * inv);
        o.w = pack2(a6 * inv, a7 * inv);
        ((uint4*)aggr)[(size_t)v * 16 + li] = o;
    }
}

// ---------------------------------------------------------------------------
// fused SAGE layer via MFMA: out = relu([aggr|xin](Mx256) @ W(256x128) + bl)
// 8 waves/block (512 thr), 16 rows/wave = 128 rows/block. Full weight tile
// staged once in 64KB LDS; LDS re-used (barrier-protected) for coalesced
// 16B output stores. In-place safe.
#define SO_STRIDE 136   // ushorts per staged row (16B-aligned, bank-spread)
__global__ __launch_bounds__(512) void sage_mfma_kernel(const ushort_t* __restrict__ xin,
                                                        const ushort_t* __restrict__ aggr,
                                                        const ushort_t* __restrict__ Bp,
                                                        const float* __restrict__ bl,
                                                        ushort_t* __restrict__ out, int M) {
    __shared__ ushort_t sB[32768];   // 64 KB
    const int tid = threadIdx.x;
    {   // cooperative 64KB load: 4096 x 16B over 512 threads
        const uint4* s = (const uint4*)Bp;
        uint4* d = (uint4*)sB;
        #pragma unroll
        for (int i = 0; i < 8; ++i)
            d[tid + 512 * i] = s[tid + 512 * i];
    }
    __syncthreads();

    const int wave = tid >> 6;            // 0..7
    const int lane = tid & 63;
    const int grp  = lane >> 4;
    const int li   = lane & 15;
    const int rowBase = (blockIdx.x * 8 + wave) * 16;
    const int arow = min(rowBase + li, M - 1);

    short8v afrag[8];
    #pragma unroll
    for (int kt = 0; kt < 4; ++kt)
        afrag[kt] = *(const short8v*)(aggr + (size_t)arow * FH + kt * 32 + grp * 8);
    #pragma unroll
    for (int kt = 0; kt < 4; ++kt)
        afrag[4 + kt] = *(const short8v*)(xin + (size_t)arow * FH + kt * 32 + grp * 8);

    float4v acc[8];
    #pragma unroll
    for (int nt = 0; nt < 8; ++nt) {
        acc[nt] = (float4v){0.f, 0.f, 0.f, 0.f};
        #pragma unroll
        for (int kt = 0; kt < 8; ++kt) {
            const short8v b = *(const short8v*)(sB + (((nt * 8 + kt) * 64) + lane) * 8);
            acc[nt] = __builtin_amdgcn_mfma_f32_16x16x32_bf16(afrag[kt], b, acc[nt], 0, 0, 0);
        }
    }

    __syncthreads();   // all waves finished reading sB; re-use it as sOut

    // stage bf16 outputs: wave-private [16][SO_STRIDE] region (8 x 4.25KB)
    ushort_t* so = sB + wave * (16 * SO_STRIDE);
    #pragma unroll
    for (int nt = 0; nt < 8; ++nt) {
        const float bias = bl[nt * 16 + li];
        #pragma unroll
        for (int r = 0; r < 4; ++r)
            so[(grp * 4 + r) * SO_STRIDE + nt * 16 + li] = f2bf(fmaxf(acc[nt][r] + bias, 0.f));
    }
    // wave-private region: same-wave LDS program order + lgkmcnt suffices
    #pragma unroll
    for (int t = 0; t < 4; ++t) {
        const int idx = lane + 64 * t;       // 0..255
        const int r  = idx >> 4;             // staged row 0..15
        const int ch = idx & 15;             // uint4 chunk within the row
        const int row = rowBase + r;
        if (row < M) {
            const uint4 val = *(const uint4*)(so + r * SO_STRIDE + ch * 8);
            *(uint4*)(out + (size_t)row * FH + ch * 8) = val;
        }
    }
}

// ---------------------------------------------------------------------------
// fused head: per-group mean pool -> relu(gmean@W4+b4) -> log_softmax(g2@W5+b5)
__global__ __launch_bounds__(256) void head_kernel(const ushort_t* __restrict__ h,
                                                   const int* __restrict__ gstart,
                                                   const float* __restrict__ W4,
                                                   const float* __restrict__ b4,
                                                   const float* __restrict__ W5,
                                                   const float* __restrict__ b5,
                                                   float* __restrict__ out, int G) {
    __shared__ float sred[4][FH];
    __shared__ float sg2[64];
    __shared__ float sl[10];
    __shared__ float slse;
    const int g = blockIdx.x;
    const int t = threadIdx.x;
    const int wave = t >> 6, lane = t & 63;
    const int beg = gstart[g], end = gstart[g + 1];

    const uint32* hp = (const uint32*)h + lane;
    float a0 = 0.f, a1 = 0.f;
    for (int i = beg + wave; i < end; i += 4) {
        const uint32 w = hp[(size_t)i * 64];
        a0 += bf_lo(w); a1 += bf_hi(w);
    }
    sred[wave][lane * 2]     = a0;
    sred[wave][lane * 2 + 1] = a1;
    __syncthreads();
    if (t < FH) {
        const float s = sred[0][t] + sred[1][t] + sred[2][t] + sred[3][t];
        sred[0][t] = s / (float)max(end - beg, 1);   // gmean
    }
    __syncthreads();
    if (t < 64) {
        float acc = b4[t];
        #pragma unroll 4
        for (int k = 0; k < FH; ++k)
            acc += sred[0][k] * W4[k * 64 + t];
        sg2[t] = fmaxf(acc, 0.f);
    }
    __syncthreads();
    if (t < 10) {
        float acc = b5[t];
        #pragma unroll 4
        for (int k = 0; k < 64; ++k)
            acc += sg2[k] * W5[k * 10 + t];
        sl[t] = acc;
    }
    __syncthreads();
    if (t == 0) {
        float m = sl[0];
        #pragma unroll
        for (int j = 1; j < 10; ++j) m = fmaxf(m, sl[j]);
        float s = 0.f;
        #pragma unroll
        for (int j = 0; j < 10; ++j) s += expf(sl[j] - m);
        slse = m + logf(s);
    }
    __syncthreads();
    if (t < 10) out[g * 10 + t] = sl[t] - slse;
}

// ---------------------------------------------------------------------------
extern "C" void kernel_launch(void* const* d_in, const int* in_sizes, int n_in,
                              void* d_out, int out_size, void* d_ws, size_t ws_size,
                              hipStream_t stream) {
    const float* x     = (const float*)d_in[0];
    const int*   ei    = (const int*)d_in[1];
    const int*   batch = (const int*)d_in[2];
    const float* Wl1 = (const float*)d_in[3];
    const float* bl1 = (const float*)d_in[4];
    const float* Wr1 = (const float*)d_in[5];
    const float* Wl2 = (const float*)d_in[6];
    const float* bl2 = (const float*)d_in[7];
    const float* Wr2 = (const float*)d_in[8];
    const float* Wl3 = (const float*)d_in[9];
    const float* bl3 = (const float*)d_in[10];
    const float* Wr3 = (const float*)d_in[11];
    const float* W4  = (const float*)d_in[12];
    const float* b4  = (const float*)d_in[13];
    const float* W5  = (const float*)d_in[14];
    const float* b5  = (const float*)d_in[15];
    float* out = (float*)d_out;

    const int N = in_sizes[0] / FH;   // 50000
    const int E = in_sizes[1] / 2;    // 600000
    const int G = out_size / 10;      // 500
    const int* src = ei;
    const int* dst = ei + E;

    // ---- workspace layout (256B-aligned chunks)
    char* p = (char*)d_ws;
    auto take = [&](size_t bytes) { char* q = p; p += (bytes + 255) & ~(size_t)255; return q; };
    ushort_t* xb    = (ushort_t*)take((size_t)N * FH * 2);
    ushort_t* h     = (ushort_t*)take((size_t)N * FH * 2);
    ushort_t* aggrb = (ushort_t*)take((size_t)N * FH * 2);
    int* deg        = (int*)take((size_t)N * 4);
    int* rowptr     = (int*)take((size_t)(N + 1) * 4);
    int* pos        = (int*)take((size_t)N * 4);
    int* csr        = (int*)take((size_t)E * 4);
    int* blockSums  = (int*)take(256 * 4);
    ushort_t* Bp1   = (ushort_t*)take(256 * FH * 2);
    ushort_t* Bp2   = (ushort_t*)take(256 * FH * 2);
    ushort_t* Bp3   = (ushort_t*)take(256 * FH * 2);
    int* gstart     = (int*)take((size_t)(G + 1) * 4);

    int nb = (N + 1023) / 1024;   // 49 scan blocks

    // ---- prep: cvt + packs
    const int cvtBlocks = (int)(((size_t)N * FH / 8 + 255) / 256);
    prep_kernel<<<cvtBlocks + 384, 256, 0, stream>>>(
        x, xb, (size_t)N * FH, cvtBlocks,
        Wl1, Wr1, Bp1, Wl2, Wr2, Bp2, Wl3, Wr3, Bp3);

    // ---- cooperative CSR build (zero|deg|scan1+gb|scan3|fill, grid-synced)
    {
        int N_ = N, E_ = E, G_ = G, nb_ = nb;
        const int* src_ = src; const int* dst_ = dst;
        int* deg_ = deg; int* rowptr_ = rowptr; int* pos_ = pos; int* csr_ = csr;
        int* bsum_ = blockSums; const int* batch_ = batch; int* gstart_ = gstart;
        void* args[] = {&src_, &dst_, &deg_, &rowptr_, &pos_, &csr_, &bsum_,
                        &batch_, &gstart_, &N_, &E_, &G_, &nb_};
        hipLaunchCooperativeKernel((const void*)csr_coop_kernel,
                                   dim3(1024), dim3(256), args, 0, stream);
    }

    const int pullGrid = (N * 64 + 255) / 256;   // one wave per node
    const int gemmGrid = (N + 127) / 128;        // 128 rows/block, 8 waves

    // ---- 3 SAGE layers (split pull + MFMA; sage is in-place safe)
    pull_mean_kernel<<<pullGrid, 256, 0, stream>>>(xb, rowptr, csr, aggrb, N);
    sage_mfma_kernel<<<gemmGrid, 512, 0, stream>>>(xb, aggrb, Bp1, bl1, h, N);

    pull_mean_kernel<<<pullGrid, 256, 0, stream>>>(h, rowptr, csr, aggrb, N);
    sage_mfma_kernel<<<gemmGrid, 512, 0, stream>>>(h, aggrb, Bp2, bl2, h, N);

    pull_mean_kernel<<<pullGrid, 256, 0, stream>>>(h, rowptr, csr, aggrb, N);
    sage_mfma_kernel<<<gemmGrid, 512, 0, stream>>>(h, aggrb, Bp3, bl3, h, N);

    // ---- fused head (pool + MLP + log_softmax)
    head_kernel<<<G, 256, 0, stream>>>(h, gstart, W4, b4, W5, b5, out, G);
}

// Round 15
// 210.143 us; speedup vs baseline: 2.7262x; 2.7262x over previous
//
#include <hip/hip_runtime.h>
#include <hip/hip_bf16.h>
#include <math.h>

#define FH 128   // feature width of x and all hidden layers

typedef __attribute__((ext_vector_type(8))) short short8v;   // 8 bf16 (4 VGPRs)
typedef __attribute__((ext_vector_type(4))) float float4v;
typedef unsigned short ushort_t;
typedef unsigned int   uint32;

__device__ __forceinline__ ushort_t f2bf(float f) {          // RNE float->bf16
    uint32 u = __builtin_bit_cast(uint32, f);
    u += 0x7fffu + ((u >> 16) & 1u);
    return (ushort_t)(u >> 16);
}
__device__ __forceinline__ float bf_lo(uint32 w) { return __builtin_bit_cast(float, w << 16); }
__device__ __forceinline__ float bf_hi(uint32 w) { return __builtin_bit_cast(float, w & 0xffff0000u); }
__device__ __forceinline__ uint32 pack2(float lo, float hi) {
    return (uint32)f2bf(lo) | ((uint32)f2bf(hi) << 16);
}

// ---------------------------------------------------------------------------
// pack: Bp[((nt*8+kt)*64 + lane)*8 + j] = W[k][n],
//   nt=n>>4, kt=k>>5, lane=(n&15)+16*((k>>3)&3), j=k&7   (W = [Wl;Wr], 256x128)
__device__ __forceinline__ void pack_one(const float* __restrict__ Wl,
                                         const float* __restrict__ Wr,
                                         ushort_t* __restrict__ Bp, int t) {
    int k = t >> 7, n = t & 127;
    float v = (k < FH) ? Wl[k * FH + n] : Wr[(k - FH) * FH + n];
    int nt = n >> 4, kt = k >> 5;
    int lane = (n & 15) + (((k >> 3) & 3) << 4);
    int j = k & 7;
    Bp[(((nt * 8 + kt) * 64) + lane) * 8 + j] = f2bf(v);
}

// prep: cvt x->bf16 | 3 weight packs | zero deg (deg consumed by a LATER
// kernel launch, so zeroing in any block order here is safe)
__global__ __launch_bounds__(256) void prep_kernel(
        const float* __restrict__ x, ushort_t* __restrict__ xb, size_t n, int cvtBlocks,
        const float* __restrict__ Wl1, const float* __restrict__ Wr1, ushort_t* __restrict__ Bp1,
        const float* __restrict__ Wl2, const float* __restrict__ Wr2, ushort_t* __restrict__ Bp2,
        const float* __restrict__ Wl3, const float* __restrict__ Wr3, ushort_t* __restrict__ Bp3,
        int* __restrict__ deg, int N) {
    int b = blockIdx.x;
    if (b < cvtBlocks) {
        size_t base = ((size_t)b * 256 + threadIdx.x) * 8;
        if (base >= n) return;
        const float4 a = *(const float4*)(x + base);
        const float4 c = *(const float4*)(x + base + 4);
        ushort_t o[8] = {f2bf(a.x), f2bf(a.y), f2bf(a.z), f2bf(a.w),
                         f2bf(c.x), f2bf(c.y), f2bf(c.z), f2bf(c.w)};
        *(uint4*)(xb + base) = *(const uint4*)o;
        return;
    }
    b -= cvtBlocks;
    if (b < 384) {                               // weight packs
        int which = b >> 7;
        int t = (b & 127) * 256 + threadIdx.x;
        if (which == 0)      pack_one(Wl1, Wr1, Bp1, t);
        else if (which == 1) pack_one(Wl2, Wr2, Bp2, t);
        else                 pack_one(Wl3, Wr3, Bp3, t);
        return;
    }
    b -= 384;
    {                                            // zero deg
        int i = (b * 256 + threadIdx.x) * 4;
        if (i + 3 < N) {
            *(int4*)(deg + i) = make_int4(0, 0, 0, 0);
        } else {
            for (int j = i; j < N; ++j) deg[j] = 0;
        }
    }
}

// in-degree count
__global__ __launch_bounds__(256) void deg_kernel(const int* __restrict__ dst,
                                                  int* __restrict__ deg, int E) {
    int e = blockIdx.x * 256 + threadIdx.x;
    if (e < E) atomicAdd(&deg[dst[e]], 1);
}

// ---------------------------------------------------------------------------
// CSR build: scan1 computes per-block exclusive scan + block sums
__global__ __launch_bounds__(256) void scan1_kernel(const int* __restrict__ deg,
                                                    int* __restrict__ rowptr,
                                                    int* __restrict__ blockSums, int N) {
    __shared__ int lds[256];
    const int base = blockIdx.x * 1024;
    const int t = threadIdx.x;
    int v[4]; int sum = 0;
    #pragma unroll
    for (int j = 0; j < 4; ++j) {
        int idx = base + t * 4 + j;
        v[j] = (idx < N) ? deg[idx] : 0;
        sum += v[j];
    }
    lds[t] = sum; __syncthreads();
    for (int off = 1; off < 256; off <<= 1) {
        int val = lds[t];
        int add = (t >= off) ? lds[t - off] : 0;
        __syncthreads();
        lds[t] = val + add;
        __syncthreads();
    }
    int run = (t > 0) ? lds[t - 1] : 0;
    #pragma unroll
    for (int j = 0; j < 4; ++j) {
        int idx = base + t * 4 + j;
        if (idx < N) rowptr[idx] = run;
        run += v[j];
    }
    if (t == 255) blockSums[blockIdx.x] = lds[255];
}

// scan3: per-block prefix of blockSums via 64-lane reduce, adds offset,
// writes pos[] copy, sets rowptr[N]=E. Blocks >= nb do group bounds.
__global__ __launch_bounds__(256) void scan3_gb_kernel(int* __restrict__ rowptr,
                                                       int* __restrict__ pos,
                                                       const int* __restrict__ blockSums,
                                                       int N, int nb,
                                                       const int* __restrict__ batch,
                                                       int* __restrict__ gstart, int G) {
    if ((int)blockIdx.x >= nb) {                 // group bounds (sorted batch)
        int g = ((int)blockIdx.x - nb) * 256 + threadIdx.x;
        if (g > G) return;
        int lo = 0, hi = N;
        while (lo < hi) {
            int mid = (lo + hi) >> 1;
            if (batch[mid] < g) lo = mid + 1; else hi = mid;
        }
        gstart[g] = lo;
        return;
    }
    __shared__ int sAdd, sTot;
    if (threadIdx.x < 64) {
        const int lane = threadIdx.x;
        const int bid = blockIdx.x;
        int pre = 0, tot = 0;
        for (int i = lane; i < nb; i += 64) {
            const int v = blockSums[i];
            tot += v;
            if (i < bid) pre += v;
        }
        #pragma unroll
        for (int off = 1; off < 64; off <<= 1) {
            pre += __shfl_xor(pre, off);
            tot += __shfl_xor(tot, off);
        }
        if (lane == 0) { sAdd = pre; sTot = tot; }
    }
    __syncthreads();
    const int add = sAdd;
    const int base = blockIdx.x * 1024;
    #pragma unroll
    for (int j = 0; j < 4; ++j) {
        int idx = base + threadIdx.x * 4 + j;
        if (idx < N) {
            int v = rowptr[idx] + add;
            rowptr[idx] = v;
            pos[idx] = v;
        }
    }
    if (blockIdx.x == (unsigned)(nb - 1) && threadIdx.x == 0) rowptr[N] = sTot;
}

// 2 edges per thread (int2 loads of src/dst)
__global__ __launch_bounds__(256) void fill_csr_kernel(const int* __restrict__ src,
                                                       const int* __restrict__ dst,
                                                       int* __restrict__ pos,
                                                       int* __restrict__ csr, int E) {
    int e = (blockIdx.x * 256 + threadIdx.x) * 2;
    if (e >= E) return;
    if (e + 1 < E) {
        const int2 s2 = *(const int2*)(src + e);
        const int2 d2 = *(const int2*)(dst + e);
        int i0 = atomicAdd(&pos[d2.x], 1);
        int i1 = atomicAdd(&pos[d2.y], 1);
        csr[i0] = s2.x;
        csr[i1] = s2.y;
    } else {
        int idx = atomicAdd(&pos[dst[e]], 1);
        csr[idx] = src[e];
    }
}

// ---------------------------------------------------------------------------
// pull aggregation (bf16 in/out, fp32 accumulate): one wave per dst node.
// 6-deep predicated prologue: covers deg<=24 (Poisson(12): ~99.9% of nodes)
// with all row loads independent & in flight; rare tail loop beyond.
__global__ __launch_bounds__(256) void pull_mean_kernel(const ushort_t* __restrict__ x,
                                                        const int* __restrict__ rowptr,
                                                        const int* __restrict__ csr,
                                                        ushort_t* __restrict__ aggr, int N) {
    const int v = (blockIdx.x * 256 + threadIdx.x) >> 6;
    if (v >= N) return;
    const int lane = threadIdx.x & 63;
    const int grp  = lane >> 4;        // which of 4 concurrent edges
    const int li   = lane & 15;        // uint4 column within the row
    const int beg = rowptr[v], end = rowptr[v + 1];
    const uint4* xp = (const uint4*)x + li;    // row = 16 uint4 (256B)

    const uint4 z = {0u, 0u, 0u, 0u};
    uint4 w0 = z, w1 = z, w2 = z, w3 = z, w4 = z, w5 = z;
    const int i0 = beg + grp;
    if (i0 < end)      w0 = xp[(size_t)csr[i0] * 16];
    if (i0 + 4 < end)  w1 = xp[(size_t)csr[i0 + 4] * 16];
    if (i0 + 8 < end)  w2 = xp[(size_t)csr[i0 + 8] * 16];
    if (i0 + 12 < end) w3 = xp[(size_t)csr[i0 + 12] * 16];
    if (i0 + 16 < end) w4 = xp[(size_t)csr[i0 + 16] * 16];
    if (i0 + 20 < end) w5 = xp[(size_t)csr[i0 + 20] * 16];

    float a0 = (bf_lo(w0.x) + bf_lo(w1.x)) + (bf_lo(w2.x) + bf_lo(w3.x)) + (bf_lo(w4.x) + bf_lo(w5.x));
    float a1 = (bf_hi(w0.x) + bf_hi(w1.x)) + (bf_hi(w2.x) + bf_hi(w3.x)) + (bf_hi(w4.x) + bf_hi(w5.x));
    float a2 = (bf_lo(w0.y) + bf_lo(w1.y)) + (bf_lo(w2.y) + bf_lo(w3.y)) + (bf_lo(w4.y) + bf_lo(w5.y));
    float a3 = (bf_hi(w0.y) + bf_hi(w1.y)) + (bf_hi(w2.y) + bf_hi(w3.y)) + (bf_hi(w4.y) + bf_hi(w5.y));
    float a4 = (bf_lo(w0.z) + bf_lo(w1.z)) + (bf_lo(w2.z) + bf_lo(w3.z)) + (bf_lo(w4.z) + bf_lo(w5.z));
    float a5 = (bf_hi(w0.z) + bf_hi(w1.z)) + (bf_hi(w2.z) + bf_hi(w3.z)) + (bf_hi(w4.z) + bf_hi(w5.z));
    float a6 = (bf_lo(w0.w) + bf_lo(w1.w)) + (bf_lo(w2.w) + bf_lo(w3.w)) + (bf_lo(w4.w) + bf_lo(w5.w));
    float a7 = (bf_hi(w0.w) + bf_hi(w1.w)) + (bf_hi(w2.w) + bf_hi(w3.w)) + (bf_hi(w4.w) + bf_hi(w5.w));

    for (int i = beg + 24 + grp; i < end; i += 4) {   // rare tail (deg > 24)
        const uint4 w = xp[(size_t)csr[i] * 16];
        a0 += bf_lo(w.x); a1 += bf_hi(w.x); a2 += bf_lo(w.y); a3 += bf_hi(w.y);
        a4 += bf_lo(w.z); a5 += bf_hi(w.z); a6 += bf_lo(w.w); a7 += bf_hi(w.w);
    }

    // combine the 4 group partials
    a0 += __shfl_xor(a0, 16); a1 += __shfl_xor(a1, 16);
    a2 += __shfl_xor(a2, 16); a3 += __shfl_xor(a3, 16);
    a4 += __shfl_xor(a4, 16); a5 += __shfl_xor(a5, 16);
    a6 += __shfl_xor(a6, 16); a7 += __shfl_xor(a7, 16);
    a0 += __shfl_xor(a0, 32); a1 += __shfl_xor(a1, 32);
    a2 += __shfl_xor(a2, 32); a3 += __shfl_xor(a3, 32);
    a4 += __shfl_xor(a4, 32); a5 += __shfl_xor(a5, 32);
    a6 += __shfl_xor(a6, 32); a7 += __shfl_xor(a7, 32);

    if (grp == 0) {
        const float inv = 1.0f / (float)max(end - beg, 1);
        uint4 o;
        o.x = pack2(a0 * inv, a1 * inv);
        o.y = pack2(a2 * inv, a3 * inv);
        o.z = pack2(a4 * inv, a5 * inv);
        o.w = pack2(a6 * inv, a7 * inv);
        ((uint4*)aggr)[(size_t)v * 16 + li] = o;
    }
}

// ---------------------------------------------------------------------------
// fused SAGE layer via MFMA: out = relu([aggr|xin](Mx256) @ W(256x128) + bl)
// 8 waves/block (512 thr), 16 rows/wave = 128 rows/block: halves the weight
// staging traffic vs 4-wave blocks (391 x 64KB = 25MB/layer) at equal wave
// concurrency. Full weight tile staged once in 64KB LDS; LDS re-used
// (barrier-protected) for coalesced 16B output stores. In-place safe.
#define SO_STRIDE 136   // ushorts per staged row (16B-aligned, bank-spread)
__global__ __launch_bounds__(512) void sage_mfma_kernel(const ushort_t* __restrict__ xin,
                                                        const ushort_t* __restrict__ aggr,
                                                        const ushort_t* __restrict__ Bp,
                                                        const float* __restrict__ bl,
                                                        ushort_t* __restrict__ out, int M) {
    __shared__ ushort_t sB[32768];   // 64 KB
    const int tid = threadIdx.x;
    {   // cooperative 64KB load: 4096 x 16B over 512 threads
        const uint4* s = (const uint4*)Bp;
        uint4* d = (uint4*)sB;
        #pragma unroll
        for (int i = 0; i < 8; ++i)
            d[tid + 512 * i] = s[tid + 512 * i];
    }
    __syncthreads();

    const int wave = tid >> 6;            // 0..7
    const int lane = tid & 63;
    const int grp  = lane >> 4;
    const int li   = lane & 15;
    const int rowBase = (blockIdx.x * 8 + wave) * 16;
    const int arow = min(rowBase + li, M - 1);

    short8v afrag[8];
    #pragma unroll
    for (int kt = 0; kt < 4; ++kt)
        afrag[kt] = *(const short8v*)(aggr + (size_t)arow * FH + kt * 32 + grp * 8);
    #pragma unroll
    for (int kt = 0; kt < 4; ++kt)
        afrag[4 + kt] = *(const short8v*)(xin + (size_t)arow * FH + kt * 32 + grp * 8);

    float4v acc[8];
    #pragma unroll
    for (int nt = 0; nt < 8; ++nt) {
        acc[nt] = (float4v){0.f, 0.f, 0.f, 0.f};
        #pragma unroll
        for (int kt = 0; kt < 8; ++kt) {
            const short8v b = *(const short8v*)(sB + (((nt * 8 + kt) * 64) + lane) * 8);
            acc[nt] = __builtin_amdgcn_mfma_f32_16x16x32_bf16(afrag[kt], b, acc[nt], 0, 0, 0);
        }
    }

    __syncthreads();   // all waves finished reading sB; re-use it as sOut

    // stage bf16 outputs: wave-private [16][SO_STRIDE] region (8 x 4.25KB)
    ushort_t* so = sB + wave * (16 * SO_STRIDE);
    #pragma unroll
    for (int nt = 0; nt < 8; ++nt) {
        const float bias = bl[nt * 16 + li];
        #pragma unroll
        for (int r = 0; r < 4; ++r)
            so[(grp * 4 + r) * SO_STRIDE + nt * 16 + li] = f2bf(fmaxf(acc[nt][r] + bias, 0.f));
    }
    // wave-private region: same-wave LDS program order + lgkmcnt suffices
    #pragma unroll
    for (int t = 0; t < 4; ++t) {
        const int idx = lane + 64 * t;       // 0..255
        const int r  = idx >> 4;             // staged row 0..15
        const int ch = idx & 15;             // uint4 chunk within the row
        const int row = rowBase + r;
        if (row < M) {
            const uint4 val = *(const uint4*)(so + r * SO_STRIDE + ch * 8);
            *(uint4*)(out + (size_t)row * FH + ch * 8) = val;
        }
    }
}

// ---------------------------------------------------------------------------
// fused head: per-group mean pool -> relu(gmean@W4+b4) -> log_softmax(g2@W5+b5)
__global__ __launch_bounds__(256) void head_kernel(const ushort_t* __restrict__ h,
                                                   const int* __restrict__ gstart,
                                                   const float* __restrict__ W4,
                                                   const float* __restrict__ b4,
                                                   const float* __restrict__ W5,
                                                   const float* __restrict__ b5,
                                                   float* __restrict__ out, int G) {
    __shared__ float sred[4][FH];
    __shared__ float sg2[64];
    __shared__ float sl[10];
    __shared__ float slse;
    const int g = blockIdx.x;
    const int t = threadIdx.x;
    const int wave = t >> 6, lane = t & 63;
    const int beg = gstart[g], end = gstart[g + 1];

    const uint32* hp = (const uint32*)h + lane;
    float a0 = 0.f, a1 = 0.f;
    for (int i = beg + wave; i < end; i += 4) {
        const uint32 w = hp[(size_t)i * 64];
        a0 += bf_lo(w); a1 += bf_hi(w);
    }
    sred[wave][lane * 2]     = a0;
    sred[wave][lane * 2 + 1] = a1;
    __syncthreads();
    if (t < FH) {
        const float s = sred[0][t] + sred[1][t] + sred[2][t] + sred[3][t];
        sred[0][t] = s / (float)max(end - beg, 1);   // gmean
    }
    __syncthreads();
    if (t < 64) {
        float acc = b4[t];
        #pragma unroll 4
        for (int k = 0; k < FH; ++k)
            acc += sred[0][k] * W4[k * 64 + t];
        sg2[t] = fmaxf(acc, 0.f);
    }
    __syncthreads();
    if (t < 10) {
        float acc = b5[t];
        #pragma unroll 4
        for (int k = 0; k < 64; ++k)
            acc += sg2[k] * W5[k * 10 + t];
        sl[t] = acc;
    }
    __syncthreads();
    if (t == 0) {
        float m = sl[0];
        #pragma unroll
        for (int j = 1; j < 10; ++j) m = fmaxf(m, sl[j]);
        float s = 0.f;
        #pragma unroll
        for (int j = 0; j < 10; ++j) s += expf(sl[j] - m);
        slse = m + logf(s);
    }
    __syncthreads();
    if (t < 10) out[g * 10 + t] = sl[t] - slse;
}

// ---------------------------------------------------------------------------
extern "C" void kernel_launch(void* const* d_in, const int* in_sizes, int n_in,
                              void* d_out, int out_size, void* d_ws, size_t ws_size,
                              hipStream_t stream) {
    const float* x     = (const float*)d_in[0];
    const int*   ei    = (const int*)d_in[1];
    const int*   batch = (const int*)d_in[2];
    const float* Wl1 = (const float*)d_in[3];
    const float* bl1 = (const float*)d_in[4];
    const float* Wr1 = (const float*)d_in[5];
    const float* Wl2 = (const float*)d_in[6];
    const float* bl2 = (const float*)d_in[7];
    const float* Wr2 = (const float*)d_in[8];
    const float* Wl3 = (const float*)d_in[9];
    const float* bl3 = (const float*)d_in[10];
    const float* Wr3 = (const float*)d_in[11];
    const float* W4  = (const float*)d_in[12];
    const float* b4  = (const float*)d_in[13];
    const float* W5  = (const float*)d_in[14];
    const float* b5  = (const float*)d_in[15];
    float* out = (float*)d_out;

    const int N = in_sizes[0] / FH;   // 50000
    const int E = in_sizes[1] / 2;    // 600000
    const int G = out_size / 10;      // 500
    const int* src = ei;
    const int* dst = ei + E;

    // ---- workspace layout (256B-aligned chunks)
    char* p = (char*)d_ws;
    auto take = [&](size_t bytes) { char* q = p; p += (bytes + 255) & ~(size_t)255; return q; };
    ushort_t* xb    = (ushort_t*)take((size_t)N * FH * 2);
    ushort_t* h     = (ushort_t*)take((size_t)N * FH * 2);
    ushort_t* aggrb = (ushort_t*)take((size_t)N * FH * 2);
    int* deg        = (int*)take((size_t)N * 4);
    int* rowptr     = (int*)take((size_t)(N + 1) * 4);
    int* pos        = (int*)take((size_t)N * 4);
    int* csr        = (int*)take((size_t)E * 4);
    int* blockSums  = (int*)take(256 * 4);
    ushort_t* Bp1   = (ushort_t*)take(256 * FH * 2);
    ushort_t* Bp2   = (ushort_t*)take(256 * FH * 2);
    ushort_t* Bp3   = (ushort_t*)take(256 * FH * 2);
    int* gstart     = (int*)take((size_t)(G + 1) * 4);

    const int nb = (N + 1023) / 1024;

    // ---- prep: cvt + packs + zero-deg (deg used only after this kernel)
    const int cvtBlocks  = (int)(((size_t)N * FH / 8 + 255) / 256);
    const int zeroBlocks = (N / 4 + 255) / 256;
    prep_kernel<<<cvtBlocks + 384 + zeroBlocks, 256, 0, stream>>>(
        x, xb, (size_t)N * FH, cvtBlocks,
        Wl1, Wr1, Bp1, Wl2, Wr2, Bp2, Wl3, Wr3, Bp3,
        deg, N);

    // ---- in-degree count
    deg_kernel<<<(E + 255) / 256, 256, 0, stream>>>(dst, deg, E);

    // ---- CSR build
    const int gbBlocks = (G + 1 + 255) / 256;
    scan1_kernel<<<nb, 256, 0, stream>>>(deg, rowptr, blockSums, N);
    scan3_gb_kernel<<<nb + gbBlocks, 256, 0, stream>>>(rowptr, pos, blockSums, N, nb,
                                                       batch, gstart, G);
    fill_csr_kernel<<<(E / 2 + 255) / 256, 256, 0, stream>>>(src, dst, pos, csr, E);

    const int pullGrid = (N * 64 + 255) / 256;   // one wave per node
    const int gemmGrid = (N + 127) / 128;        // 128 rows/block, 8 waves

    // ---- 3 SAGE layers (split pull + MFMA; sage is in-place safe)
    pull_mean_kernel<<<pullGrid, 256, 0, stream>>>(xb, rowptr, csr, aggrb, N);
    sage_mfma_kernel<<<gemmGrid, 512, 0, stream>>>(xb, aggrb, Bp1, bl1, h, N);

    pull_mean_kernel<<<pullGrid, 256, 0, stream>>>(h, rowptr, csr, aggrb, N);
    sage_mfma_kernel<<<gemmGrid, 512, 0, stream>>>(h, aggrb, Bp2, bl2, h, N);

    pull_mean_kernel<<<pullGrid, 256, 0, stream>>>(h, rowptr, csr, aggrb, N);
    sage_mfma_kernel<<<gemmGrid, 512, 0, stream>>>(h, aggrb, Bp3, bl3, h, N);

    // ---- fused head (pool + MLP + log_softmax)
    head_kernel<<<G, 256, 0, stream>>>(h, gstart, W4, b4, W5, b5, out, G);
}